// Round 1
// baseline (917.893 us; speedup 1.0000x reference)
//
#include <hip/hip_runtime.h>

// ---------------- CSR build ----------------

__global__ __launch_bounds__(256) void hist_kernel(const int* __restrict__ dst,
                                                   int* __restrict__ count, int E) {
    int e = blockIdx.x * 256 + threadIdx.x;
    if (e < E) atomicAdd(&count[dst[e]], 1);
}

__global__ __launch_bounds__(1024) void scan_a(const int* __restrict__ count,
                                               int* __restrict__ incl,
                                               int* __restrict__ bsum, int N) {
    __shared__ int s[1024];
    int tid = threadIdx.x;
    int i = blockIdx.x * 1024 + tid;
    int v = (i < N) ? count[i] : 0;
    s[tid] = v;
    __syncthreads();
    for (int off = 1; off < 1024; off <<= 1) {
        int t = (tid >= off) ? s[tid - off] : 0;
        __syncthreads();
        s[tid] += t;
        __syncthreads();
    }
    if (i < N) incl[i] = s[tid];
    if (tid == 1023) bsum[blockIdx.x] = s[1023];
}

__global__ void scan_b(const int* __restrict__ bsum, int* __restrict__ boff, int NB) {
    if (threadIdx.x == 0 && blockIdx.x == 0) {
        int run = 0;
        for (int b = 0; b < NB; ++b) { int c = bsum[b]; boff[b] = run; run += c; }
    }
}

__global__ __launch_bounds__(1024) void scan_c(const int* __restrict__ count,
                                               const int* __restrict__ incl,
                                               const int* __restrict__ boff,
                                               int* __restrict__ rowptr,
                                               int* __restrict__ cursor, int N) {
    int i = blockIdx.x * 1024 + threadIdx.x;
    if (i < N) {
        int excl = incl[i] - count[i] + boff[blockIdx.x];
        rowptr[i] = excl;
        cursor[i] = excl;
        if (i == N - 1) rowptr[N] = incl[i] + boff[blockIdx.x];
    }
}

__global__ __launch_bounds__(256) void scatter_kernel(const int* __restrict__ src,
                                                      const int* __restrict__ dst,
                                                      const float* __restrict__ val,
                                                      int* __restrict__ cursor,
                                                      int* __restrict__ ssrc,
                                                      float* __restrict__ sval, int E) {
    int e = blockIdx.x * 256 + threadIdx.x;
    if (e < E) {
        int d = dst[e];
        int pos = atomicAdd(&cursor[d], 1);
        ssrc[pos] = src[e];
        sval[pos] = val[e];
    }
}

// ---------------- GEMM1: [M,512] @ [512,128] + bias ----------------
// BM=128, BN=128(all), BK=16; 256 threads, 8x8 micro-tile.

__global__ __launch_bounds__(256) void gemm1(const float* __restrict__ X,
                                             const float* __restrict__ W,
                                             const float* __restrict__ bias,
                                             float* __restrict__ out, int M) {
    __shared__ float As[16][132];
    __shared__ float Bs[16][132];
    int t = threadIdx.x;
    int bm = blockIdx.x * 128;
    int tx = t & 15, ty = t >> 4;

    float acc[8][8];
#pragma unroll
    for (int i = 0; i < 8; i++)
#pragma unroll
        for (int j = 0; j < 8; j++) acc[i][j] = 0.f;

    int arow = t >> 1;
    int asub = (t & 1) * 8;
    int brow = t >> 4;
    int bcol = (t & 15) * 8;
    bool avalid = (bm + arow) < M;
    const float* aptr = X + (size_t)(bm + arow) * 512 + asub;
    const float* bptr = W + (size_t)brow * 128 + bcol;

    for (int k0 = 0; k0 < 512; k0 += 16) {
        float4 a0, a1;
        if (avalid) {
            a0 = *(const float4*)(aptr + k0);
            a1 = *(const float4*)(aptr + k0 + 4);
        } else {
            a0 = make_float4(0.f, 0.f, 0.f, 0.f);
            a1 = a0;
        }
        float4 b0 = *(const float4*)(bptr + (size_t)k0 * 128);
        float4 b1 = *(const float4*)(bptr + (size_t)k0 * 128 + 4);
        __syncthreads();
        As[asub + 0][arow] = a0.x; As[asub + 1][arow] = a0.y;
        As[asub + 2][arow] = a0.z; As[asub + 3][arow] = a0.w;
        As[asub + 4][arow] = a1.x; As[asub + 5][arow] = a1.y;
        As[asub + 6][arow] = a1.z; As[asub + 7][arow] = a1.w;
        *(float4*)&Bs[brow][bcol] = b0;
        *(float4*)&Bs[brow][bcol + 4] = b1;
        __syncthreads();
#pragma unroll
        for (int kk = 0; kk < 16; ++kk) {
            float a[8], b[8];
#pragma unroll
            for (int i = 0; i < 8; i++) a[i] = As[kk][ty * 8 + i];
#pragma unroll
            for (int j = 0; j < 8; j++) b[j] = Bs[kk][tx * 8 + j];
#pragma unroll
            for (int i = 0; i < 8; i++)
#pragma unroll
                for (int j = 0; j < 8; j++) acc[i][j] += a[i] * b[j];
        }
    }
    float bv[8];
#pragma unroll
    for (int j = 0; j < 8; j++) bv[j] = bias[tx * 8 + j];
#pragma unroll
    for (int i = 0; i < 8; i++) {
        int row = bm + ty * 8 + i;
        if (row < M) {
            float* o = out + (size_t)row * 128 + tx * 8;
            float4 r0 = make_float4(acc[i][0] + bv[0], acc[i][1] + bv[1],
                                    acc[i][2] + bv[2], acc[i][3] + bv[3]);
            float4 r1 = make_float4(acc[i][4] + bv[4], acc[i][5] + bv[5],
                                    acc[i][6] + bv[6], acc[i][7] + bv[7]);
            *(float4*)o = r0;
            *(float4*)(o + 4) = r1;
        }
    }
}

// ---------------- GEMM2: relu([M,128]) @ [128,64] + bias ----------------
// 16 nodes/block, 16 threads/node, 4 outf/thread.

__global__ __launch_bounds__(256) void gemm2(const float* __restrict__ H,
                                             const float* __restrict__ W,
                                             const float* __restrict__ bias,
                                             float* __restrict__ out, int M) {
    __shared__ float Ws[128 * 64];
    __shared__ float Xs[16 * 132];
    int t = threadIdx.x;
    int m0 = blockIdx.x * 16;
#pragma unroll
    for (int i = 0; i < 8; i++) {
        int idx = t + i * 256;
        ((float4*)Ws)[idx] = ((const float4*)W)[idx];
    }
#pragma unroll
    for (int i = 0; i < 2; i++) {
        int idx = t + i * 256;
        int gi = idx * 4;
        int row = gi >> 7, col = gi & 127;
        float4 v = make_float4(0.f, 0.f, 0.f, 0.f);
        if (m0 + row < M) v = *(const float4*)(H + (size_t)(m0 + row) * 128 + col);
        v.x = fmaxf(v.x, 0.f); v.y = fmaxf(v.y, 0.f);
        v.z = fmaxf(v.z, 0.f); v.w = fmaxf(v.w, 0.f);
        *(float4*)&Xs[row * 132 + col] = v;
    }
    __syncthreads();
    int node = t >> 4;
    int fg = t & 15;
    float4 acc = make_float4(0.f, 0.f, 0.f, 0.f);
#pragma unroll 4
    for (int k = 0; k < 128; ++k) {
        float xv = Xs[node * 132 + k];
        float4 w = *(const float4*)&Ws[k * 64 + fg * 4];
        acc.x += xv * w.x; acc.y += xv * w.y;
        acc.z += xv * w.z; acc.w += xv * w.w;
    }
    int row = m0 + node;
    if (row < M) {
        float4 bb = *(const float4*)(bias + fg * 4);
        acc.x += bb.x; acc.y += bb.y; acc.z += bb.z; acc.w += bb.w;
        *(float4*)(out + (size_t)row * 64 + fg * 4) = acc;
    }
}

// ---------------- GEMM3: relu([M,64]) @ [64,16] + bias ----------------
// 32 nodes/block, 8 threads/node, 2 outf/thread.

__global__ __launch_bounds__(256) void gemm3(const float* __restrict__ H,
                                             const float* __restrict__ W,
                                             const float* __restrict__ bias,
                                             float* __restrict__ out, int M) {
    __shared__ float Ws[64 * 16];
    __shared__ float Xs[32 * 68];
    int t = threadIdx.x;
    int m0 = blockIdx.x * 32;
    ((float4*)Ws)[t] = ((const float4*)W)[t];  // 256 float4 == 1024 floats
#pragma unroll
    for (int i = 0; i < 2; i++) {
        int idx = t + i * 256;
        int gi = idx * 4;
        int row = gi >> 6, col = gi & 63;
        float4 v = make_float4(0.f, 0.f, 0.f, 0.f);
        if (m0 + row < M) v = *(const float4*)(H + (size_t)(m0 + row) * 64 + col);
        v.x = fmaxf(v.x, 0.f); v.y = fmaxf(v.y, 0.f);
        v.z = fmaxf(v.z, 0.f); v.w = fmaxf(v.w, 0.f);
        *(float4*)&Xs[row * 68 + col] = v;
    }
    __syncthreads();
    int node = t >> 3;
    int j = t & 7;
    float a0 = 0.f, a1 = 0.f;
#pragma unroll 8
    for (int k = 0; k < 64; ++k) {
        float xv = Xs[node * 68 + k];
        a0 += xv * Ws[k * 16 + j * 2];
        a1 += xv * Ws[k * 16 + j * 2 + 1];
    }
    int row = m0 + node;
    if (row < M) {
        a0 += bias[j * 2];
        a1 += bias[j * 2 + 1];
        float2 r = make_float2(a0, a1);
        *(float2*)(out + (size_t)row * 16 + j * 2) = r;
    }
}

// ---------------- CSR SpMM kernels ----------------

__global__ __launch_bounds__(256) void spmm128(const int* __restrict__ rowptr,
                                               const int* __restrict__ ssrc,
                                               const float* __restrict__ sval,
                                               const float* __restrict__ T,
                                               float* __restrict__ H, int N) {
    int lane = threadIdx.x & 63;
    int node = __builtin_amdgcn_readfirstlane(blockIdx.x * 4 + (threadIdx.x >> 6));
    if (node >= N) return;
    int beg = rowptr[node], end = rowptr[node + 1];
    float a0 = 0.f, a1 = 0.f;
    for (int i = beg; i < end; ++i) {
        int s = ssrc[i];
        float v = sval[i];
        const float* p = T + (size_t)s * 128;
        a0 += v * p[lane];
        a1 += v * p[lane + 64];
    }
    float* o = H + (size_t)node * 128;
    o[lane] = a0;
    o[lane + 64] = a1;
}

__global__ __launch_bounds__(256) void spmm64(const int* __restrict__ rowptr,
                                              const int* __restrict__ ssrc,
                                              const float* __restrict__ sval,
                                              const float* __restrict__ T,
                                              float* __restrict__ H, int N) {
    int lane = threadIdx.x & 63;
    int node = __builtin_amdgcn_readfirstlane(blockIdx.x * 4 + (threadIdx.x >> 6));
    if (node >= N) return;
    int beg = rowptr[node], end = rowptr[node + 1];
    float a = 0.f;
    for (int i = beg; i < end; ++i) a += sval[i] * T[(size_t)ssrc[i] * 64 + lane];
    H[(size_t)node * 64 + lane] = a;
}

// SpMM over 16 logits fused with argmax (first-max tie-break, matches numpy).
__global__ __launch_bounds__(256) void spmm_argmax(const int* __restrict__ rowptr,
                                                   const int* __restrict__ ssrc,
                                                   const float* __restrict__ sval,
                                                   const float* __restrict__ T,
                                                   int* __restrict__ out, int N) {
    int lane = threadIdx.x & 63;
    int wave = threadIdx.x >> 6;
    int sub = lane >> 4;
    int fl = lane & 15;
    int node = blockIdx.x * 16 + wave * 4 + sub;
    float acc = 0.f;
    if (node < N) {
        int beg = rowptr[node], end = rowptr[node + 1];
        for (int i = beg; i < end; ++i)
            acc += sval[i] * T[(size_t)ssrc[i] * 16 + fl];
    }
    float bv = acc;
    int bi = fl;
#pragma unroll
    for (int off = 8; off >= 1; off >>= 1) {
        float ov = __shfl_xor(bv, off, 64);
        int oi = __shfl_xor(bi, off, 64);
        if (ov > bv || (ov == bv && oi < bi)) { bv = ov; bi = oi; }
    }
    if (node < N && fl == 0) out[node] = bi;
}

// ---------------- launch ----------------

extern "C" void kernel_launch(void* const* d_in, const int* in_sizes, int n_in,
                              void* d_out, int out_size, void* d_ws, size_t ws_size,
                              hipStream_t stream) {
    const float* x  = (const float*)d_in[0];
    const int*   ei = (const int*)d_in[1];
    const float* ev = (const float*)d_in[2];
    const float* W1 = (const float*)d_in[3];
    const float* b1 = (const float*)d_in[4];
    const float* W2 = (const float*)d_in[5];
    const float* b2 = (const float*)d_in[6];
    const float* W3 = (const float*)d_in[7];
    const float* b3 = (const float*)d_in[8];
    int* out = (int*)d_out;

    int M = in_sizes[0] / 512;
    int E = in_sizes[2];
    const int* src = ei;
    const int* dst = ei + E;

    char* ws = (char*)d_ws;
    size_t off = 0;
    auto alloc = [&](size_t bytes) {
        size_t o = off;
        off += (bytes + 255) & ~(size_t)255;
        return o;
    };
    float* tA     = (float*)(ws + alloc((size_t)M * 128 * 4));  // t1 / t2 / t3
    float* hB     = (float*)(ws + alloc((size_t)M * 128 * 4));  // h1 / h2
    int*   ssrc   = (int*)  (ws + alloc((size_t)E * 4));
    float* sval   = (float*)(ws + alloc((size_t)E * 4));
    int*   rowptr = (int*)  (ws + alloc((size_t)(M + 1) * 4));
    int*   cursor = (int*)  (ws + alloc((size_t)M * 4));
    int*   count  = (int*)  (ws + alloc((size_t)M * 4));
    int*   incl   = (int*)  (ws + alloc((size_t)M * 4));
    int*   bsum   = (int*)  (ws + alloc(4096));
    int*   boff   = (int*)  (ws + alloc(4096));

    // ---- CSR build (by dst) ----
    hipMemsetAsync(count, 0, (size_t)M * 4, stream);
    hist_kernel<<<(E + 255) / 256, 256, 0, stream>>>(dst, count, E);
    int NB = (M + 1023) / 1024;
    scan_a<<<NB, 1024, 0, stream>>>(count, incl, bsum, M);
    scan_b<<<1, 64, 0, stream>>>(bsum, boff, NB);
    scan_c<<<NB, 1024, 0, stream>>>(count, incl, boff, rowptr, cursor, M);
    scatter_kernel<<<(E + 255) / 256, 256, 0, stream>>>(src, dst, ev, cursor, ssrc, sval, E);

    // ---- layer 1 ----
    gemm1<<<(M + 127) / 128, 256, 0, stream>>>(x, W1, b1, tA, M);
    spmm128<<<(M + 3) / 4, 256, 0, stream>>>(rowptr, ssrc, sval, tA, hB, M);
    // ---- layer 2 (relu fused into gemm2 input) ----
    gemm2<<<(M + 15) / 16, 256, 0, stream>>>(hB, W2, b2, tA, M);
    spmm64<<<(M + 3) / 4, 256, 0, stream>>>(rowptr, ssrc, sval, tA, hB, M);
    // ---- layer 3 + argmax ----
    gemm3<<<(M + 31) / 32, 256, 0, stream>>>(hB, W3, b3, tA, M);
    spmm_argmax<<<(M + 15) / 16, 256, 0, stream>>>(rowptr, ssrc, sval, tA, out, M);
}

// Round 2
// 860.907 us; speedup vs baseline: 1.0662x; 1.0662x over previous
//
#include <hip/hip_runtime.h>

typedef _Float16 half8 __attribute__((ext_vector_type(8)));
typedef float floatx4 __attribute__((ext_vector_type(4)));

// ---------------- CSR build ----------------

__global__ __launch_bounds__(256) void hist_kernel(const int* __restrict__ dst,
                                                   int* __restrict__ count, int E) {
    int e = blockIdx.x * 256 + threadIdx.x;
    if (e < E) atomicAdd(&count[dst[e]], 1);
}

__global__ __launch_bounds__(1024) void scan_a(const int* __restrict__ count,
                                               int* __restrict__ incl,
                                               int* __restrict__ bsum, int N) {
    __shared__ int s[1024];
    int tid = threadIdx.x;
    int i = blockIdx.x * 1024 + tid;
    int v = (i < N) ? count[i] : 0;
    s[tid] = v;
    __syncthreads();
    for (int off = 1; off < 1024; off <<= 1) {
        int t = (tid >= off) ? s[tid - off] : 0;
        __syncthreads();
        s[tid] += t;
        __syncthreads();
    }
    if (i < N) incl[i] = s[tid];
    if (tid == 1023) bsum[blockIdx.x] = s[1023];
}

__global__ void scan_b(const int* __restrict__ bsum, int* __restrict__ boff, int NB) {
    if (threadIdx.x == 0 && blockIdx.x == 0) {
        int run = 0;
        for (int b = 0; b < NB; ++b) { int c = bsum[b]; boff[b] = run; run += c; }
    }
}

__global__ __launch_bounds__(1024) void scan_c(const int* __restrict__ count,
                                               const int* __restrict__ incl,
                                               const int* __restrict__ boff,
                                               int* __restrict__ rowptr,
                                               int* __restrict__ cursor, int N) {
    int i = blockIdx.x * 1024 + threadIdx.x;
    if (i < N) {
        int excl = incl[i] - count[i] + boff[blockIdx.x];
        rowptr[i] = excl;
        cursor[i] = excl;
        if (i == N - 1) rowptr[N] = incl[i] + boff[blockIdx.x];
    }
}

__global__ __launch_bounds__(256) void scatter_kernel(const int* __restrict__ src,
                                                      const int* __restrict__ dst,
                                                      const float* __restrict__ val,
                                                      int* __restrict__ cursor,
                                                      int* __restrict__ ssrc,
                                                      float* __restrict__ sval, int E) {
    int e = blockIdx.x * 256 + threadIdx.x;
    if (e < E) {
        int d = dst[e];
        int pos = atomicAdd(&cursor[d], 1);
        ssrc[pos] = src[e];
        sval[pos] = val[e];
    }
}

// ---------------- W1 prep: fp32 [512][128] -> fp16 hi/lo transposed [128][512] ----

__global__ __launch_bounds__(256) void prep_w1(const float* __restrict__ W1,
                                               _Float16* __restrict__ Whi,
                                               _Float16* __restrict__ Wlo) {
    int tid = blockIdx.x * 256 + threadIdx.x;   // 65536 total
    int n = tid >> 9;        // 0..127
    int k = tid & 511;       // 0..511
    float w = W1[(size_t)k * 128 + n];
    _Float16 h = (_Float16)w;
    _Float16 l = (_Float16)(w - (float)h);
    Whi[tid] = h;
    Wlo[tid] = l;
}

// ---------------- GEMM1 via split-fp16 MFMA ----------------
// C[M,128] = X[M,512] @ W1 + b1, computed as hi*hi + hi*lo + lo*hi.
// BM=64, full N=128; 4 waves arranged 2x2, each wave a 32x64 tile
// (2 m-tiles x 4 n-tiles of 16x16x32 MFMA). No LDS.

__device__ __forceinline__ void split8(float4 f0, float4 f1, half8& h, half8& l) {
    float f[8] = {f0.x, f0.y, f0.z, f0.w, f1.x, f1.y, f1.z, f1.w};
#pragma unroll
    for (int j = 0; j < 8; ++j) {
        _Float16 hi = (_Float16)f[j];
        h[j] = hi;
        l[j] = (_Float16)(f[j] - (float)hi);
    }
}

__global__ __launch_bounds__(256) void gemm1_mfma(const float* __restrict__ X,
                                                  const _Float16* __restrict__ Whi,
                                                  const _Float16* __restrict__ Wlo,
                                                  const float* __restrict__ bias,
                                                  float* __restrict__ out, int M) {
    int w = threadIdx.x >> 6;
    int lane = threadIdx.x & 63;
    int quad = lane >> 4;
    int l16 = lane & 15;
    int m0 = blockIdx.x * 64 + (w >> 1) * 32;   // wave's first row
    int n0 = (w & 1) * 64;                      // wave's first col

    // A row pointers (clamped; stores are guarded)
    int ra0 = min(m0 + l16, M - 1);
    int ra1 = min(m0 + 16 + l16, M - 1);
    const float* a0p = X + (size_t)ra0 * 512 + quad * 8;
    const float* a1p = X + (size_t)ra1 * 512 + quad * 8;

    // B frag offsets: lane reads 8 consecutive k at row n of W1T[n][k]
    int boff[4];
#pragma unroll
    for (int nt = 0; nt < 4; ++nt)
        boff[nt] = (n0 + nt * 16 + l16) * 512 + quad * 8;

    floatx4 acc[2][4];
#pragma unroll
    for (int mt = 0; mt < 2; ++mt)
#pragma unroll
        for (int nt = 0; nt < 4; ++nt)
            acc[mt][nt] = (floatx4){0.f, 0.f, 0.f, 0.f};

    for (int k0 = 0; k0 < 512; k0 += 32) {
        float4 af00 = *(const float4*)(a0p + k0);
        float4 af01 = *(const float4*)(a0p + k0 + 4);
        float4 af10 = *(const float4*)(a1p + k0);
        float4 af11 = *(const float4*)(a1p + k0 + 4);
        half8 bh[4], bl[4];
#pragma unroll
        for (int nt = 0; nt < 4; ++nt) {
            bh[nt] = *(const half8*)(Whi + boff[nt] + k0);
            bl[nt] = *(const half8*)(Wlo + boff[nt] + k0);
        }
        half8 ah0, al0, ah1, al1;
        split8(af00, af01, ah0, al0);
        split8(af10, af11, ah1, al1);
#pragma unroll
        for (int nt = 0; nt < 4; ++nt) {
            acc[0][nt] = __builtin_amdgcn_mfma_f32_16x16x32_f16(ah0, bh[nt], acc[0][nt], 0, 0, 0);
            acc[1][nt] = __builtin_amdgcn_mfma_f32_16x16x32_f16(ah1, bh[nt], acc[1][nt], 0, 0, 0);
            acc[0][nt] = __builtin_amdgcn_mfma_f32_16x16x32_f16(ah0, bl[nt], acc[0][nt], 0, 0, 0);
            acc[1][nt] = __builtin_amdgcn_mfma_f32_16x16x32_f16(ah1, bl[nt], acc[1][nt], 0, 0, 0);
            acc[0][nt] = __builtin_amdgcn_mfma_f32_16x16x32_f16(al0, bh[nt], acc[0][nt], 0, 0, 0);
            acc[1][nt] = __builtin_amdgcn_mfma_f32_16x16x32_f16(al1, bh[nt], acc[1][nt], 0, 0, 0);
        }
    }

    // Epilogue: D[row = quad*4 + r][col = l16] per 16x16 tile (m89-verified layout)
#pragma unroll
    for (int nt = 0; nt < 4; ++nt) {
        int col = n0 + nt * 16 + l16;
        float bv = bias[col];
#pragma unroll
        for (int mt = 0; mt < 2; ++mt) {
#pragma unroll
            for (int r = 0; r < 4; ++r) {
                int row = m0 + mt * 16 + quad * 4 + r;
                if (row < M) out[(size_t)row * 128 + col] = acc[mt][nt][r] + bv;
            }
        }
    }
}

// ---------------- GEMM2: relu([M,128]) @ [128,64] + bias ----------------

__global__ __launch_bounds__(256) void gemm2(const float* __restrict__ H,
                                             const float* __restrict__ W,
                                             const float* __restrict__ bias,
                                             float* __restrict__ out, int M) {
    __shared__ float Ws[128 * 64];
    __shared__ float Xs[16 * 132];
    int t = threadIdx.x;
    int m0 = blockIdx.x * 16;
#pragma unroll
    for (int i = 0; i < 8; i++) {
        int idx = t + i * 256;
        ((float4*)Ws)[idx] = ((const float4*)W)[idx];
    }
#pragma unroll
    for (int i = 0; i < 2; i++) {
        int idx = t + i * 256;
        int gi = idx * 4;
        int row = gi >> 7, col = gi & 127;
        float4 v = make_float4(0.f, 0.f, 0.f, 0.f);
        if (m0 + row < M) v = *(const float4*)(H + (size_t)(m0 + row) * 128 + col);
        v.x = fmaxf(v.x, 0.f); v.y = fmaxf(v.y, 0.f);
        v.z = fmaxf(v.z, 0.f); v.w = fmaxf(v.w, 0.f);
        *(float4*)&Xs[row * 132 + col] = v;
    }
    __syncthreads();
    int node = t >> 4;
    int fg = t & 15;
    float4 acc = make_float4(0.f, 0.f, 0.f, 0.f);
#pragma unroll 4
    for (int k = 0; k < 128; ++k) {
        float xv = Xs[node * 132 + k];
        float4 w = *(const float4*)&Ws[k * 64 + fg * 4];
        acc.x += xv * w.x; acc.y += xv * w.y;
        acc.z += xv * w.z; acc.w += xv * w.w;
    }
    int row = m0 + node;
    if (row < M) {
        float4 bb = *(const float4*)(bias + fg * 4);
        acc.x += bb.x; acc.y += bb.y; acc.z += bb.z; acc.w += bb.w;
        *(float4*)(out + (size_t)row * 64 + fg * 4) = acc;
    }
}

// ---------------- GEMM3: relu([M,64]) @ [64,16] + bias ----------------

__global__ __launch_bounds__(256) void gemm3(const float* __restrict__ H,
                                             const float* __restrict__ W,
                                             const float* __restrict__ bias,
                                             float* __restrict__ out, int M) {
    __shared__ float Ws[64 * 16];
    __shared__ float Xs[32 * 68];
    int t = threadIdx.x;
    int m0 = blockIdx.x * 32;
    ((float4*)Ws)[t] = ((const float4*)W)[t];
#pragma unroll
    for (int i = 0; i < 2; i++) {
        int idx = t + i * 256;
        int gi = idx * 4;
        int row = gi >> 6, col = gi & 63;
        float4 v = make_float4(0.f, 0.f, 0.f, 0.f);
        if (m0 + row < M) v = *(const float4*)(H + (size_t)(m0 + row) * 64 + col);
        v.x = fmaxf(v.x, 0.f); v.y = fmaxf(v.y, 0.f);
        v.z = fmaxf(v.z, 0.f); v.w = fmaxf(v.w, 0.f);
        *(float4*)&Xs[row * 68 + col] = v;
    }
    __syncthreads();
    int node = t >> 3;
    int j = t & 7;
    float a0 = 0.f, a1 = 0.f;
#pragma unroll 8
    for (int k = 0; k < 64; ++k) {
        float xv = Xs[node * 68 + k];
        a0 += xv * Ws[k * 16 + j * 2];
        a1 += xv * Ws[k * 16 + j * 2 + 1];
    }
    int row = m0 + node;
    if (row < M) {
        a0 += bias[j * 2];
        a1 += bias[j * 2 + 1];
        float2 r = make_float2(a0, a1);
        *(float2*)(out + (size_t)row * 16 + j * 2) = r;
    }
}

// ---------------- CSR SpMM kernels (edge loop unrolled x4) ----------------

__global__ __launch_bounds__(256) void spmm128(const int* __restrict__ rowptr,
                                               const int* __restrict__ ssrc,
                                               const float* __restrict__ sval,
                                               const float* __restrict__ T,
                                               float* __restrict__ H, int N) {
    int lane = threadIdx.x & 63;
    int node = __builtin_amdgcn_readfirstlane(blockIdx.x * 4 + (threadIdx.x >> 6));
    if (node >= N) return;
    int beg = rowptr[node], end = rowptr[node + 1];
    float a0 = 0.f, a1 = 0.f;
    int i = beg;
    int n4 = beg + ((end - beg) & ~3);
    for (; i < n4; i += 4) {
        int s0 = ssrc[i], s1 = ssrc[i + 1], s2 = ssrc[i + 2], s3 = ssrc[i + 3];
        float v0 = sval[i], v1 = sval[i + 1], v2 = sval[i + 2], v3 = sval[i + 3];
        const float* p0 = T + (size_t)s0 * 128;
        const float* p1 = T + (size_t)s1 * 128;
        const float* p2 = T + (size_t)s2 * 128;
        const float* p3 = T + (size_t)s3 * 128;
        float x0 = p0[lane], y0 = p0[lane + 64];
        float x1 = p1[lane], y1 = p1[lane + 64];
        float x2 = p2[lane], y2 = p2[lane + 64];
        float x3 = p3[lane], y3 = p3[lane + 64];
        a0 += v0 * x0; a1 += v0 * y0;
        a0 += v1 * x1; a1 += v1 * y1;
        a0 += v2 * x2; a1 += v2 * y2;
        a0 += v3 * x3; a1 += v3 * y3;
    }
    for (; i < end; ++i) {
        int s = ssrc[i];
        float v = sval[i];
        const float* p = T + (size_t)s * 128;
        a0 += v * p[lane];
        a1 += v * p[lane + 64];
    }
    float* o = H + (size_t)node * 128;
    o[lane] = a0;
    o[lane + 64] = a1;
}

__global__ __launch_bounds__(256) void spmm64(const int* __restrict__ rowptr,
                                              const int* __restrict__ ssrc,
                                              const float* __restrict__ sval,
                                              const float* __restrict__ T,
                                              float* __restrict__ H, int N) {
    int lane = threadIdx.x & 63;
    int node = __builtin_amdgcn_readfirstlane(blockIdx.x * 4 + (threadIdx.x >> 6));
    if (node >= N) return;
    int beg = rowptr[node], end = rowptr[node + 1];
    float a = 0.f;
    int i = beg;
    int n4 = beg + ((end - beg) & ~3);
    for (; i < n4; i += 4) {
        int s0 = ssrc[i], s1 = ssrc[i + 1], s2 = ssrc[i + 2], s3 = ssrc[i + 3];
        float v0 = sval[i], v1 = sval[i + 1], v2 = sval[i + 2], v3 = sval[i + 3];
        float x0 = T[(size_t)s0 * 64 + lane];
        float x1 = T[(size_t)s1 * 64 + lane];
        float x2 = T[(size_t)s2 * 64 + lane];
        float x3 = T[(size_t)s3 * 64 + lane];
        a += v0 * x0; a += v1 * x1; a += v2 * x2; a += v3 * x3;
    }
    for (; i < end; ++i) a += sval[i] * T[(size_t)ssrc[i] * 64 + lane];
    H[(size_t)node * 64 + lane] = a;
}

__global__ __launch_bounds__(256) void spmm_argmax(const int* __restrict__ rowptr,
                                                   const int* __restrict__ ssrc,
                                                   const float* __restrict__ sval,
                                                   const float* __restrict__ T,
                                                   int* __restrict__ out, int N) {
    int lane = threadIdx.x & 63;
    int wave = threadIdx.x >> 6;
    int sub = lane >> 4;
    int fl = lane & 15;
    int node = blockIdx.x * 16 + wave * 4 + sub;
    float acc = 0.f;
    if (node < N) {
        int beg = rowptr[node], end = rowptr[node + 1];
        int i = beg;
        int n4 = beg + ((end - beg) & ~3);
        for (; i < n4; i += 4) {
            int s0 = ssrc[i], s1 = ssrc[i + 1], s2 = ssrc[i + 2], s3 = ssrc[i + 3];
            float v0 = sval[i], v1 = sval[i + 1], v2 = sval[i + 2], v3 = sval[i + 3];
            float x0 = T[(size_t)s0 * 16 + fl];
            float x1 = T[(size_t)s1 * 16 + fl];
            float x2 = T[(size_t)s2 * 16 + fl];
            float x3 = T[(size_t)s3 * 16 + fl];
            acc += v0 * x0; acc += v1 * x1; acc += v2 * x2; acc += v3 * x3;
        }
        for (; i < end; ++i) acc += sval[i] * T[(size_t)ssrc[i] * 16 + fl];
    }
    float bv = acc;
    int bi = fl;
#pragma unroll
    for (int off = 8; off >= 1; off >>= 1) {
        float ov = __shfl_xor(bv, off, 64);
        int oi = __shfl_xor(bi, off, 64);
        if (ov > bv || (ov == bv && oi < bi)) { bv = ov; bi = oi; }
    }
    if (node < N && fl == 0) out[node] = bi;
}

// ---------------- launch ----------------

extern "C" void kernel_launch(void* const* d_in, const int* in_sizes, int n_in,
                              void* d_out, int out_size, void* d_ws, size_t ws_size,
                              hipStream_t stream) {
    const float* x  = (const float*)d_in[0];
    const int*   ei = (const int*)d_in[1];
    const float* ev = (const float*)d_in[2];
    const float* W1 = (const float*)d_in[3];
    const float* b1 = (const float*)d_in[4];
    const float* W2 = (const float*)d_in[5];
    const float* b2 = (const float*)d_in[6];
    const float* W3 = (const float*)d_in[7];
    const float* b3 = (const float*)d_in[8];
    int* out = (int*)d_out;

    int M = in_sizes[0] / 512;
    int E = in_sizes[2];
    const int* src = ei;
    const int* dst = ei + E;

    char* ws = (char*)d_ws;
    size_t off = 0;
    auto alloc = [&](size_t bytes) {
        size_t o = off;
        off += (bytes + 255) & ~(size_t)255;
        return o;
    };
    float*    tA     = (float*)(ws + alloc((size_t)M * 128 * 4));
    float*    hB     = (float*)(ws + alloc((size_t)M * 128 * 4));
    int*      ssrc   = (int*)  (ws + alloc((size_t)E * 4));
    float*    sval   = (float*)(ws + alloc((size_t)E * 4));
    int*      rowptr = (int*)  (ws + alloc((size_t)(M + 1) * 4));
    int*      cursor = (int*)  (ws + alloc((size_t)M * 4));
    int*      count  = (int*)  (ws + alloc((size_t)M * 4));
    int*      incl   = (int*)  (ws + alloc((size_t)M * 4));
    int*      bsum   = (int*)  (ws + alloc(4096));
    int*      boff   = (int*)  (ws + alloc(4096));
    _Float16* w1hi   = (_Float16*)(ws + alloc(512 * 128 * 2));
    _Float16* w1lo   = (_Float16*)(ws + alloc(512 * 128 * 2));

    // ---- CSR build (by dst) + W1 prep ----
    hipMemsetAsync(count, 0, (size_t)M * 4, stream);
    prep_w1<<<256, 256, 0, stream>>>(W1, w1hi, w1lo);
    hist_kernel<<<(E + 255) / 256, 256, 0, stream>>>(dst, count, E);
    int NB = (M + 1023) / 1024;
    scan_a<<<NB, 1024, 0, stream>>>(count, incl, bsum, M);
    scan_b<<<1, 64, 0, stream>>>(bsum, boff, NB);
    scan_c<<<NB, 1024, 0, stream>>>(count, incl, boff, rowptr, cursor, M);
    scatter_kernel<<<(E + 255) / 256, 256, 0, stream>>>(src, dst, ev, cursor, ssrc, sval, E);

    // ---- layer 1 ----
    gemm1_mfma<<<(M + 63) / 64, 256, 0, stream>>>(x, w1hi, w1lo, b1, tA, M);
    spmm128<<<(M + 3) / 4, 256, 0, stream>>>(rowptr, ssrc, sval, tA, hB, M);
    // ---- layer 2 (relu fused into gemm2 input) ----
    gemm2<<<(M + 15) / 16, 256, 0, stream>>>(hB, W2, b2, tA, M);
    spmm64<<<(M + 3) / 4, 256, 0, stream>>>(rowptr, ssrc, sval, tA, hB, M);
    // ---- layer 3 + argmax ----
    gemm3<<<(M + 31) / 32, 256, 0, stream>>>(hB, W3, b3, tA, M);
    spmm_argmax<<<(M + 15) / 16, 256, 0, stream>>>(rowptr, ssrc, sval, tA, out, M);
}

// Round 3
// 753.803 us; speedup vs baseline: 1.2177x; 1.1421x over previous
//
#include <hip/hip_runtime.h>

typedef _Float16 half8 __attribute__((ext_vector_type(8)));
typedef float floatx4 __attribute__((ext_vector_type(4)));

// global -> LDS async copy, 16B per lane. LDS dest is wave-uniform base;
// HW scatters lane i to base + i*16 (m104/m108). Integer casts build the
// AS1/AS3 pointers (LDS aperture is 4GB-aligned so low 32 bits == offset).
__device__ __forceinline__ void g2lds16(const void* g, void* l) {
    __builtin_amdgcn_global_load_lds(
        (const __attribute__((address_space(1))) void*)(unsigned long long)g,
        (__attribute__((address_space(3))) void*)(unsigned int)(unsigned long long)l,
        16, 0, 0);
}

// ---------------- CSR build ----------------

__global__ __launch_bounds__(256) void hist_kernel(const int* __restrict__ dst,
                                                   int* __restrict__ count, int E) {
    int e = blockIdx.x * 256 + threadIdx.x;
    if (e < E) atomicAdd(&count[dst[e]], 1);
}

__global__ __launch_bounds__(1024) void scan_a(const int* __restrict__ count,
                                               int* __restrict__ incl,
                                               int* __restrict__ bsum, int N) {
    __shared__ int s[1024];
    int tid = threadIdx.x;
    int i = blockIdx.x * 1024 + tid;
    int v = (i < N) ? count[i] : 0;
    s[tid] = v;
    __syncthreads();
    for (int off = 1; off < 1024; off <<= 1) {
        int t = (tid >= off) ? s[tid - off] : 0;
        __syncthreads();
        s[tid] += t;
        __syncthreads();
    }
    if (i < N) incl[i] = s[tid];
    if (tid == 1023) bsum[blockIdx.x] = s[1023];
}

__global__ void scan_b(const int* __restrict__ bsum, int* __restrict__ boff, int NB) {
    if (threadIdx.x == 0 && blockIdx.x == 0) {
        int run = 0;
        for (int b = 0; b < NB; ++b) { int c = bsum[b]; boff[b] = run; run += c; }
    }
}

__global__ __launch_bounds__(1024) void scan_c(const int* __restrict__ count,
                                               const int* __restrict__ incl,
                                               const int* __restrict__ boff,
                                               int* __restrict__ rowptr,
                                               int* __restrict__ cursor, int N) {
    int i = blockIdx.x * 1024 + threadIdx.x;
    if (i < N) {
        int excl = incl[i] - count[i] + boff[blockIdx.x];
        rowptr[i] = excl;
        cursor[i] = excl;
        if (i == N - 1) rowptr[N] = incl[i] + boff[blockIdx.x];
    }
}

__global__ __launch_bounds__(256) void scatter_kernel(const int* __restrict__ src,
                                                      const int* __restrict__ dst,
                                                      const float* __restrict__ val,
                                                      int* __restrict__ cursor,
                                                      int* __restrict__ ssrc,
                                                      float* __restrict__ sval, int E) {
    int e = blockIdx.x * 256 + threadIdx.x;
    if (e < E) {
        int d = dst[e];
        int pos = atomicAdd(&cursor[d], 1);
        ssrc[pos] = src[e];
        sval[pos] = val[e];
    }
}

// ---------------- weight prep: fp32 -> fp16 hi/lo, transposed [n][k] ----------------

__global__ __launch_bounds__(256) void prep_w1(const float* __restrict__ W1,
                                               _Float16* __restrict__ Whi,
                                               _Float16* __restrict__ Wlo) {
    int tid = blockIdx.x * 256 + threadIdx.x;   // 65536
    int n = tid >> 9;        // 0..127
    int k = tid & 511;       // 0..511
    float w = W1[(size_t)k * 128 + n];
    _Float16 h = (_Float16)w;
    Whi[tid] = h;
    Wlo[tid] = (_Float16)(w - (float)h);
}

__global__ __launch_bounds__(256) void prep_w2(const float* __restrict__ W2,
                                               _Float16* __restrict__ Whi,
                                               _Float16* __restrict__ Wlo) {
    int tid = blockIdx.x * 256 + threadIdx.x;   // 8192
    int n = tid >> 7;        // 0..63
    int k = tid & 127;       // 0..127
    float w = W2[(size_t)k * 64 + n];
    _Float16 h = (_Float16)w;
    Whi[tid] = h;
    Wlo[tid] = (_Float16)(w - (float)h);
}

__device__ __forceinline__ void split8(float4 f0, float4 f1, half8& h, half8& l) {
    float f[8] = {f0.x, f0.y, f0.z, f0.w, f1.x, f1.y, f1.z, f1.w};
#pragma unroll
    for (int j = 0; j < 8; ++j) {
        _Float16 hi = (_Float16)f[j];
        h[j] = hi;
        l[j] = (_Float16)(f[j] - (float)hi);
    }
}

// ---------------- GEMM1: [M,512]@[512,128]+b1, split-fp16 MFMA ----------------
// BM=128; wave w owns rows m0=bm+w*32 (2 m-tiles), full N=128 (8 n-tiles).
// B (hi+lo) double-buffered in LDS via global_load_lds; 1 barrier/iter.
// LDS buffer: [hi: 128 rows x 64B][lo: 128 rows x 64B] = 16 KB.
// Row stride 16 dwords -> 2-way bank aliasing (free, m136).

__global__ __launch_bounds__(256) void gemm1_mfma(const float* __restrict__ X,
                                                  const _Float16* __restrict__ Whi,
                                                  const _Float16* __restrict__ Wlo,
                                                  const float* __restrict__ bias,
                                                  float* __restrict__ out, int M) {
    __shared__ char smem[2 * 16384];
    int t = threadIdx.x;
    int w = t >> 6;
    int lane = t & 63;
    int quad = lane >> 4;
    int l16 = lane & 15;
    int bm = blockIdx.x * 128;
    int m0 = bm + w * 32;

    int ra0 = min(m0 + l16, M - 1);
    int ra1 = min(m0 + 16 + l16, M - 1);
    const float* a0p = X + (size_t)ra0 * 512 + quad * 8;
    const float* a1p = X + (size_t)ra1 * 512 + quad * 8;

    // staging: wave w owns chunks w*4..w*4+3 (1 KB each) of the 16 KB buffer
    int chunk0 = w * 4;
    const _Float16* gsrc[4];
#pragma unroll
    for (int c = 0; c < 4; ++c) {
        int idx = (chunk0 + c) * 1024 + lane * 16;  // byte index in buffer
        int sec = idx >> 13;                        // 0 = hi, 1 = lo
        int row = (idx & 8191) >> 6;                // n row
        int kch = (idx >> 4) & 3;                   // 16B chunk along k
        gsrc[c] = (sec ? Wlo : Whi) + (size_t)row * 512 + kch * 8;
    }
    // prologue: stage k0=0 into buf 0
#pragma unroll
    for (int c = 0; c < 4; ++c)
        g2lds16(gsrc[c], smem + (chunk0 + c) * 1024);

    floatx4 acc[2][8];
#pragma unroll
    for (int mt = 0; mt < 2; ++mt)
#pragma unroll
        for (int nt = 0; nt < 8; ++nt) acc[mt][nt] = (floatx4){0.f, 0.f, 0.f, 0.f};

    for (int i = 0; i < 16; ++i) {
        int k0 = i * 32;
        __syncthreads();  // buf (i&1) staged; prior reads of other buf done
        // A loads first (so consuming them leaves the stage DMAs outstanding)
        float4 af00 = *(const float4*)(a0p + k0);
        float4 af01 = *(const float4*)(a0p + k0 + 4);
        float4 af10 = *(const float4*)(a1p + k0);
        float4 af11 = *(const float4*)(a1p + k0 + 4);
        if (i < 15) {
            char* nbuf = smem + ((i + 1) & 1) * 16384;
#pragma unroll
            for (int c = 0; c < 4; ++c)
                g2lds16(gsrc[c] + k0 + 32, nbuf + (chunk0 + c) * 1024);
        }
        const char* buf = smem + (i & 1) * 16384;
        half8 bh[8], bl[8];
#pragma unroll
        for (int nt = 0; nt < 8; ++nt) {
            int off = (nt * 16 + l16) * 64 + quad * 16;
            bh[nt] = *(const half8*)(buf + off);
            bl[nt] = *(const half8*)(buf + 8192 + off);
        }
        half8 ah0, al0, ah1, al1;
        split8(af00, af01, ah0, al0);
        split8(af10, af11, ah1, al1);
#pragma unroll
        for (int nt = 0; nt < 8; ++nt) {
            acc[0][nt] = __builtin_amdgcn_mfma_f32_16x16x32_f16(ah0, bh[nt], acc[0][nt], 0, 0, 0);
            acc[1][nt] = __builtin_amdgcn_mfma_f32_16x16x32_f16(ah1, bh[nt], acc[1][nt], 0, 0, 0);
            acc[0][nt] = __builtin_amdgcn_mfma_f32_16x16x32_f16(ah0, bl[nt], acc[0][nt], 0, 0, 0);
            acc[1][nt] = __builtin_amdgcn_mfma_f32_16x16x32_f16(ah1, bl[nt], acc[1][nt], 0, 0, 0);
            acc[0][nt] = __builtin_amdgcn_mfma_f32_16x16x32_f16(al0, bh[nt], acc[0][nt], 0, 0, 0);
            acc[1][nt] = __builtin_amdgcn_mfma_f32_16x16x32_f16(al1, bh[nt], acc[1][nt], 0, 0, 0);
        }
    }

    // D[row = quad*4+r][col = l16] per 16x16 tile (m89-verified)
#pragma unroll
    for (int nt = 0; nt < 8; ++nt) {
        int col = nt * 16 + l16;
        float bv = bias[col];
#pragma unroll
        for (int mt = 0; mt < 2; ++mt)
#pragma unroll
            for (int r = 0; r < 4; ++r) {
                int row = m0 + mt * 16 + quad * 4 + r;
                if (row < M) out[(size_t)row * 128 + col] = acc[mt][nt][r] + bv;
            }
    }
}

// ---------------- GEMM2: relu([M,128])@[128,64]+b2, split-fp16 MFMA ----------------
// W2T hi/lo staged once in LDS (padded rows: 320B stride -> 2-way, free).
// BM=128, wave w owns rows m0=bm+w*32, full N=64 (4 n-tiles). One barrier total.

__global__ __launch_bounds__(256) void gemm2_mfma(const float* __restrict__ H,
                                                  const _Float16* __restrict__ Whi,
                                                  const _Float16* __restrict__ Wlo,
                                                  const float* __restrict__ bias,
                                                  float* __restrict__ out, int M) {
    __shared__ char smem[2 * 64 * 320];  // 40960 B
    int t = threadIdx.x;
#pragma unroll
    for (int i = 0; i < 4; ++i) {
        int gidx = i * 256 + t;          // 0..1023 float4s
        int row = gidx >> 4, col = gidx & 15;
        *(float4*)(smem + row * 320 + col * 16) = ((const float4*)Whi)[gidx];
        *(float4*)(smem + 20480 + row * 320 + col * 16) = ((const float4*)Wlo)[gidx];
    }
    __syncthreads();

    int w = t >> 6;
    int lane = t & 63;
    int quad = lane >> 4;
    int l16 = lane & 15;
    int m0 = blockIdx.x * 128 + w * 32;
    int ra0 = min(m0 + l16, M - 1);
    int ra1 = min(m0 + 16 + l16, M - 1);
    const float* a0p = H + (size_t)ra0 * 128 + quad * 8;
    const float* a1p = H + (size_t)ra1 * 128 + quad * 8;

    floatx4 acc[2][4];
#pragma unroll
    for (int mt = 0; mt < 2; ++mt)
#pragma unroll
        for (int nt = 0; nt < 4; ++nt) acc[mt][nt] = (floatx4){0.f, 0.f, 0.f, 0.f};

#pragma unroll
    for (int k0 = 0; k0 < 128; k0 += 32) {
        float4 af00 = *(const float4*)(a0p + k0);
        float4 af01 = *(const float4*)(a0p + k0 + 4);
        float4 af10 = *(const float4*)(a1p + k0);
        float4 af11 = *(const float4*)(a1p + k0 + 4);
        af00.x = fmaxf(af00.x, 0.f); af00.y = fmaxf(af00.y, 0.f);
        af00.z = fmaxf(af00.z, 0.f); af00.w = fmaxf(af00.w, 0.f);
        af01.x = fmaxf(af01.x, 0.f); af01.y = fmaxf(af01.y, 0.f);
        af01.z = fmaxf(af01.z, 0.f); af01.w = fmaxf(af01.w, 0.f);
        af10.x = fmaxf(af10.x, 0.f); af10.y = fmaxf(af10.y, 0.f);
        af10.z = fmaxf(af10.z, 0.f); af10.w = fmaxf(af10.w, 0.f);
        af11.x = fmaxf(af11.x, 0.f); af11.y = fmaxf(af11.y, 0.f);
        af11.z = fmaxf(af11.z, 0.f); af11.w = fmaxf(af11.w, 0.f);
        half8 bh[4], bl[4];
#pragma unroll
        for (int nt = 0; nt < 4; ++nt) {
            int off = (nt * 16 + l16) * 320 + k0 * 2 + quad * 16;
            bh[nt] = *(const half8*)(smem + off);
            bl[nt] = *(const half8*)(smem + 20480 + off);
        }
        half8 ah0, al0, ah1, al1;
        split8(af00, af01, ah0, al0);
        split8(af10, af11, ah1, al1);
#pragma unroll
        for (int nt = 0; nt < 4; ++nt) {
            acc[0][nt] = __builtin_amdgcn_mfma_f32_16x16x32_f16(ah0, bh[nt], acc[0][nt], 0, 0, 0);
            acc[1][nt] = __builtin_amdgcn_mfma_f32_16x16x32_f16(ah1, bh[nt], acc[1][nt], 0, 0, 0);
            acc[0][nt] = __builtin_amdgcn_mfma_f32_16x16x32_f16(ah0, bl[nt], acc[0][nt], 0, 0, 0);
            acc[1][nt] = __builtin_amdgcn_mfma_f32_16x16x32_f16(ah1, bl[nt], acc[1][nt], 0, 0, 0);
            acc[0][nt] = __builtin_amdgcn_mfma_f32_16x16x32_f16(al0, bh[nt], acc[0][nt], 0, 0, 0);
            acc[1][nt] = __builtin_amdgcn_mfma_f32_16x16x32_f16(al1, bh[nt], acc[1][nt], 0, 0, 0);
        }
    }

#pragma unroll
    for (int nt = 0; nt < 4; ++nt) {
        int col = nt * 16 + l16;
        float bv = bias[col];
#pragma unroll
        for (int mt = 0; mt < 2; ++mt)
#pragma unroll
            for (int r = 0; r < 4; ++r) {
                int row = m0 + mt * 16 + quad * 4 + r;
                if (row < M) out[(size_t)row * 64 + col] = acc[mt][nt][r] + bv;
            }
    }
}

// ---------------- GEMM3: relu([M,64]) @ [64,16] + bias ----------------

__global__ __launch_bounds__(256) void gemm3(const float* __restrict__ H,
                                             const float* __restrict__ W,
                                             const float* __restrict__ bias,
                                             float* __restrict__ out, int M) {
    __shared__ float Ws[64 * 16];
    __shared__ float Xs[32 * 68];
    int t = threadIdx.x;
    int m0 = blockIdx.x * 32;
    ((float4*)Ws)[t] = ((const float4*)W)[t];
#pragma unroll
    for (int i = 0; i < 2; i++) {
        int idx = t + i * 256;
        int gi = idx * 4;
        int row = gi >> 6, col = gi & 63;
        float4 v = make_float4(0.f, 0.f, 0.f, 0.f);
        if (m0 + row < M) v = *(const float4*)(H + (size_t)(m0 + row) * 64 + col);
        v.x = fmaxf(v.x, 0.f); v.y = fmaxf(v.y, 0.f);
        v.z = fmaxf(v.z, 0.f); v.w = fmaxf(v.w, 0.f);
        *(float4*)&Xs[row * 68 + col] = v;
    }
    __syncthreads();
    int node = t >> 3;
    int j = t & 7;
    float a0 = 0.f, a1 = 0.f;
#pragma unroll 8
    for (int k = 0; k < 64; ++k) {
        float xv = Xs[node * 68 + k];
        a0 += xv * Ws[k * 16 + j * 2];
        a1 += xv * Ws[k * 16 + j * 2 + 1];
    }
    int row = m0 + node;
    if (row < M) {
        a0 += bias[j * 2];
        a1 += bias[j * 2 + 1];
        float2 r = make_float2(a0, a1);
        *(float2*)(out + (size_t)row * 16 + j * 2) = r;
    }
}

// ---------------- CSR SpMM kernels (edge loop unrolled x4) ----------------

__global__ __launch_bounds__(256) void spmm128(const int* __restrict__ rowptr,
                                               const int* __restrict__ ssrc,
                                               const float* __restrict__ sval,
                                               const float* __restrict__ T,
                                               float* __restrict__ H, int N) {
    int lane = threadIdx.x & 63;
    int node = __builtin_amdgcn_readfirstlane(blockIdx.x * 4 + (threadIdx.x >> 6));
    if (node >= N) return;
    int beg = rowptr[node], end = rowptr[node + 1];
    float a0 = 0.f, a1 = 0.f;
    int i = beg;
    int n4 = beg + ((end - beg) & ~3);
    for (; i < n4; i += 4) {
        int s0 = ssrc[i], s1 = ssrc[i + 1], s2 = ssrc[i + 2], s3 = ssrc[i + 3];
        float v0 = sval[i], v1 = sval[i + 1], v2 = sval[i + 2], v3 = sval[i + 3];
        const float* p0 = T + (size_t)s0 * 128;
        const float* p1 = T + (size_t)s1 * 128;
        const float* p2 = T + (size_t)s2 * 128;
        const float* p3 = T + (size_t)s3 * 128;
        float x0 = p0[lane], y0 = p0[lane + 64];
        float x1 = p1[lane], y1 = p1[lane + 64];
        float x2 = p2[lane], y2 = p2[lane + 64];
        float x3 = p3[lane], y3 = p3[lane + 64];
        a0 += v0 * x0; a1 += v0 * y0;
        a0 += v1 * x1; a1 += v1 * y1;
        a0 += v2 * x2; a1 += v2 * y2;
        a0 += v3 * x3; a1 += v3 * y3;
    }
    for (; i < end; ++i) {
        int s = ssrc[i];
        float v = sval[i];
        const float* p = T + (size_t)s * 128;
        a0 += v * p[lane];
        a1 += v * p[lane + 64];
    }
    float* o = H + (size_t)node * 128;
    o[lane] = a0;
    o[lane + 64] = a1;
}

__global__ __launch_bounds__(256) void spmm64(const int* __restrict__ rowptr,
                                              const int* __restrict__ ssrc,
                                              const float* __restrict__ sval,
                                              const float* __restrict__ T,
                                              float* __restrict__ H, int N) {
    int lane = threadIdx.x & 63;
    int node = __builtin_amdgcn_readfirstlane(blockIdx.x * 4 + (threadIdx.x >> 6));
    if (node >= N) return;
    int beg = rowptr[node], end = rowptr[node + 1];
    float a = 0.f;
    int i = beg;
    int n4 = beg + ((end - beg) & ~3);
    for (; i < n4; i += 4) {
        int s0 = ssrc[i], s1 = ssrc[i + 1], s2 = ssrc[i + 2], s3 = ssrc[i + 3];
        float v0 = sval[i], v1 = sval[i + 1], v2 = sval[i + 2], v3 = sval[i + 3];
        float x0 = T[(size_t)s0 * 64 + lane];
        float x1 = T[(size_t)s1 * 64 + lane];
        float x2 = T[(size_t)s2 * 64 + lane];
        float x3 = T[(size_t)s3 * 64 + lane];
        a += v0 * x0; a += v1 * x1; a += v2 * x2; a += v3 * x3;
    }
    for (; i < end; ++i) a += sval[i] * T[(size_t)ssrc[i] * 64 + lane];
    H[(size_t)node * 64 + lane] = a;
}

__global__ __launch_bounds__(256) void spmm_argmax(const int* __restrict__ rowptr,
                                                   const int* __restrict__ ssrc,
                                                   const float* __restrict__ sval,
                                                   const float* __restrict__ T,
                                                   int* __restrict__ out, int N) {
    int lane = threadIdx.x & 63;
    int wave = threadIdx.x >> 6;
    int sub = lane >> 4;
    int fl = lane & 15;
    int node = blockIdx.x * 16 + wave * 4 + sub;
    float acc = 0.f;
    if (node < N) {
        int beg = rowptr[node], end = rowptr[node + 1];
        int i = beg;
        int n4 = beg + ((end - beg) & ~3);
        for (; i < n4; i += 4) {
            int s0 = ssrc[i], s1 = ssrc[i + 1], s2 = ssrc[i + 2], s3 = ssrc[i + 3];
            float v0 = sval[i], v1 = sval[i + 1], v2 = sval[i + 2], v3 = sval[i + 3];
            float x0 = T[(size_t)s0 * 16 + fl];
            float x1 = T[(size_t)s1 * 16 + fl];
            float x2 = T[(size_t)s2 * 16 + fl];
            float x3 = T[(size_t)s3 * 16 + fl];
            acc += v0 * x0; acc += v1 * x1; acc += v2 * x2; acc += v3 * x3;
        }
        for (; i < end; ++i) acc += sval[i] * T[(size_t)ssrc[i] * 16 + fl];
    }
    float bv = acc;
    int bi = fl;
#pragma unroll
    for (int off = 8; off >= 1; off >>= 1) {
        float ov = __shfl_xor(bv, off, 64);
        int oi = __shfl_xor(bi, off, 64);
        if (ov > bv || (ov == bv && oi < bi)) { bv = ov; bi = oi; }
    }
    if (node < N && fl == 0) out[node] = bi;
}

// ---------------- launch ----------------

extern "C" void kernel_launch(void* const* d_in, const int* in_sizes, int n_in,
                              void* d_out, int out_size, void* d_ws, size_t ws_size,
                              hipStream_t stream) {
    const float* x  = (const float*)d_in[0];
    const int*   ei = (const int*)d_in[1];
    const float* ev = (const float*)d_in[2];
    const float* W1 = (const float*)d_in[3];
    const float* b1 = (const float*)d_in[4];
    const float* W2 = (const float*)d_in[5];
    const float* b2 = (const float*)d_in[6];
    const float* W3 = (const float*)d_in[7];
    const float* b3 = (const float*)d_in[8];
    int* out = (int*)d_out;

    int M = in_sizes[0] / 512;
    int E = in_sizes[2];
    const int* src = ei;
    const int* dst = ei + E;

    char* ws = (char*)d_ws;
    size_t off = 0;
    auto alloc = [&](size_t bytes) {
        size_t o = off;
        off += (bytes + 255) & ~(size_t)255;
        return o;
    };
    float*    tA     = (float*)(ws + alloc((size_t)M * 128 * 4));
    float*    hB     = (float*)(ws + alloc((size_t)M * 128 * 4));
    int*      ssrc   = (int*)  (ws + alloc((size_t)E * 4));
    float*    sval   = (float*)(ws + alloc((size_t)E * 4));
    int*      rowptr = (int*)  (ws + alloc((size_t)(M + 1) * 4));
    int*      cursor = (int*)  (ws + alloc((size_t)M * 4));
    int*      count  = (int*)  (ws + alloc((size_t)M * 4));
    int*      incl   = (int*)  (ws + alloc((size_t)M * 4));
    int*      bsum   = (int*)  (ws + alloc(4096));
    int*      boff   = (int*)  (ws + alloc(4096));
    _Float16* w1hi   = (_Float16*)(ws + alloc(512 * 128 * 2));
    _Float16* w1lo   = (_Float16*)(ws + alloc(512 * 128 * 2));
    _Float16* w2hi   = (_Float16*)(ws + alloc(128 * 64 * 2));
    _Float16* w2lo   = (_Float16*)(ws + alloc(128 * 64 * 2));

    // ---- CSR build (by dst) + weight prep ----
    hipMemsetAsync(count, 0, (size_t)M * 4, stream);
    prep_w1<<<256, 256, 0, stream>>>(W1, w1hi, w1lo);
    prep_w2<<<32, 256, 0, stream>>>(W2, w2hi, w2lo);
    hist_kernel<<<(E + 255) / 256, 256, 0, stream>>>(dst, count, E);
    int NB = (M + 1023) / 1024;
    scan_a<<<NB, 1024, 0, stream>>>(count, incl, bsum, M);
    scan_b<<<1, 64, 0, stream>>>(bsum, boff, NB);
    scan_c<<<NB, 1024, 0, stream>>>(count, incl, boff, rowptr, cursor, M);
    scatter_kernel<<<(E + 255) / 256, 256, 0, stream>>>(src, dst, ev, cursor, ssrc, sval, E);

    // ---- layer 1 ----
    gemm1_mfma<<<(M + 127) / 128, 256, 0, stream>>>(x, w1hi, w1lo, b1, tA, M);
    spmm128<<<(M + 3) / 4, 256, 0, stream>>>(rowptr, ssrc, sval, tA, hB, M);
    // ---- layer 2 (relu fused into gemm2 input) ----
    gemm2_mfma<<<(M + 127) / 128, 256, 0, stream>>>(hB, w2hi, w2lo, b2, tA, M);
    spmm64<<<(M + 3) / 4, 256, 0, stream>>>(rowptr, ssrc, sval, tA, hB, M);
    // ---- layer 3 + argmax ----
    gemm3<<<(M + 31) / 32, 256, 0, stream>>>(hB, W3, b3, tA, M);
    spmm_argmax<<<(M + 15) / 16, 256, 0, stream>>>(rowptr, ssrc, sval, tA, out, M);
}